// Round 4
// baseline (103.513 us; speedup 1.0000x reference)
//
#include <hip/hip_runtime.h>
#include <hip/hip_bf16.h>
#include <math.h>
#include <string.h>

#define NPTS 524288
#define KC 32
#define DIM 64
#define GRIDX 2048
#define ITERS 2   // GRIDX * 4 waves * 32 pts * ITERS == NPTS

typedef __attribute__((ext_vector_type(8)))  short short8v;
typedef __attribute__((ext_vector_type(16))) float f32x16;

// ws byte layout: W bf16[32][128] @0 (8192B) | C float[32] @8192 | acc float[4128] @8320
#define ACC_FLOATS (KC + KC * 128)

// LDS byte map (per block) — total 49792 B -> 3 blocks/CU (149376 <= 163840)
//   xt:  w*8192       [32 pt][256B rows]   byte = pt*256 + (colB ^ ((pt&7)<<4))
//   rl:  32768+w*4096 [32 comp][128B rows] byte = comp*128 + (colB ^ ((comp&7)<<4))
//   cl:  49152  C[32] floats
//   dem: 49280  demsc[4][32] floats
//   epilogue scratch overlays [0, 49152): three 16-KB regions for waves 1,2,3
#define RL_BASE  32768
#define CL_BASE  49152
#define DEM_BASE 49280
#define SMEM_BYTES 49792

__device__ __forceinline__ short f2bf(float f) {              // RNE (prep only)
    unsigned u = __float_as_uint(f);
    unsigned r = (u + 0x7FFFu + ((u >> 16) & 1u)) >> 16;
    return (short)r;
}

__device__ __forceinline__ unsigned short s2bf(float a) {
    __hip_bfloat16 h = __float2bfloat16(a);
    unsigned short u;
    memcpy(&u, &h, 2);
    return u;
}

__device__ __forceinline__ unsigned pk2bf(float a, float b) { // compiler -> v_cvt_pk_bf16_f32
    return (unsigned)s2bf(a) | ((unsigned)s2bf(b) << 16);
}

__global__ void gmm_prep(const float* __restrict__ mu, const float* __restrict__ var,
                         const float* __restrict__ pi, short* __restrict__ W,
                         float* __restrict__ C) {
    int t = threadIdx.x + blockIdx.x * blockDim.x;
    if (t < KC * 128) {
        int k = t >> 7, d = t & 127;
        float iv = 1.0f / var[k * DIM + (d & 63)];
        float v = (d < DIM) ? mu[k * DIM + d] * iv : -0.5f * iv;
        W[t] = f2bf(v);
    }
    if (t < KC) {
        const float LOG2PI = 1.8378770664093453f;
        float s = 0.0f;
        for (int d = 0; d < DIM; ++d) {
            float v = var[t * DIM + d];
            float m = mu[t * DIM + d];
            s += m * m / v + logf(v);
        }
        C[t] = logf(pi[t]) - 0.5f * (s + DIM * LOG2PI);
    }
}

__device__ __forceinline__ void stage_chunk(unsigned char* xt, int c, float4 v, int l) {
    int pt   = c * 4 + (l >> 4);
    int colB = (l & 15) * 8;          // d0 * 2 bytes
    int swz  = (pt & 7) << 4;
    uint2 bx, bx2;
    bx.x  = pk2bf(v.x, v.y);          bx.y  = pk2bf(v.z, v.w);
    bx2.x = pk2bf(v.x * v.x, v.y * v.y);
    bx2.y = pk2bf(v.z * v.z, v.w * v.w);
    *(uint2*)(xt + pt * 256 + (colB ^ swz))         = bx;
    *(uint2*)(xt + pt * 256 + ((128 + colB) ^ swz)) = bx2;
}

__global__ __launch_bounds__(256, 3)
void gmm_main(const float* __restrict__ X, const short* __restrict__ W,
              const float* __restrict__ C, float* __restrict__ acc) {
    __shared__ unsigned char smem[SMEM_BYTES];

    const int tid = threadIdx.x;
    const int l   = tid & 63;
    const int w   = tid >> 6;
    const int lm  = l & 31;
    const int lh  = l >> 5;

    if (tid < KC) ((float*)(smem + CL_BASE))[tid] = C[tid];

    unsigned char* xt = smem + w * 8192;
    unsigned char* rl = smem + RL_BASE + w * 4096;
    const float* cl = (const float*)(smem + CL_BASE);

    // Resident W fragments: A[m=comp=lm][k = ks*16 + lh*8 + j]
    short8v wf[8];
#pragma unroll
    for (int ks = 0; ks < 8; ++ks)
        wf[ks] = *(const short8v*)(W + lm * 128 + ks * 16 + lh * 8);

    f32x16 rxacc[4];
#pragma unroll
    for (int nt = 0; nt < 4; ++nt)
#pragma unroll
        for (int i = 0; i < 16; ++i) rxacc[nt][i] = 0.0f;
    float demacc[16];
#pragma unroll
    for (int r = 0; r < 16; ++r) demacc[r] = 0.0f;

    __syncthreads();   // cl ready

    const float4* X4 = (const float4*)X;
    float4 xrA[4], xrB[4];
    {
        size_t t0 = ((size_t)blockIdx.x * 4 + w) * 512;
#pragma unroll
        for (int c = 0; c < 4; ++c) xrA[c] = X4[t0 + c * 64 + l];
    }

#pragma unroll
    for (int it = 0; it < ITERS; ++it) {
        size_t tf = ((size_t)(it * GRIDX + blockIdx.x) * 4 + w) * 512;
        // issue loads for chunks 4..7 of THIS tile (latency hides under staging 0..3)
#pragma unroll
        for (int c = 0; c < 4; ++c) xrB[c] = X4[tf + (c + 4) * 64 + l];
        // convert + store chunks 0..3 from xrA
#pragma unroll
        for (int c = 0; c < 4; ++c) stage_chunk(xt, c, xrA[c], l);
        // prefetch NEXT tile chunks 0..3 (xrA regs free now; latency hides under GEMMs)
        if (it + 1 < ITERS) {
            size_t tn = ((size_t)((it + 1) * GRIDX + blockIdx.x) * 4 + w) * 512;
#pragma unroll
            for (int c = 0; c < 4; ++c) xrA[c] = X4[tn + c * 64 + l];
        }
        // convert + store chunks 4..7 from xrB
#pragma unroll
        for (int c = 0; c < 4; ++c) stage_chunk(xt, c + 4, xrB[c], l);

        // ---- GEMM-1: S[comp][pt] = C[comp] + sum_d W[comp][d2] * xt[pt][d2] ----
        f32x16 s;
#pragma unroll
        for (int r = 0; r < 16; ++r) s[r] = cl[(r & 3) + 8 * (r >> 2) + 4 * lh];
#pragma unroll
        for (int ks = 0; ks < 8; ++ks) {
            short8v b = *(const short8v*)(xt + lm * 256 + ((ks * 32 + lh * 16) ^ ((lm & 7) << 4)));
            s = __builtin_amdgcn_mfma_f32_32x32x16_bf16(wf[ks], b, s, 0, 0, 0);
        }

        // ---- softmax over 32 comps for col pt=lm (halves l and l^32 split comps) ----
        float m = s[0];
#pragma unroll
        for (int r = 1; r < 16; ++r) m = fmaxf(m, s[r]);
        m = fmaxf(m, __shfl_xor(m, 32, 64));
        float sum = 0.0f;
#pragma unroll
        for (int r = 0; r < 16; ++r) { s[r] = __expf(s[r] - m); sum += s[r]; }
        sum += __shfl_xor(sum, 32, 64);
        float inv = 1.0f / sum;
#pragma unroll
        for (int r = 0; r < 16; ++r) {
            float rv = s[r] * inv;
            demacc[r] += rv;
            int comp = (r & 3) + 8 * (r >> 2) + 4 * lh;
            *(unsigned short*)(rl + comp * 128 + ((lm * 2) ^ ((comp & 7) << 4))) = s2bf(rv);
        }

        // ---- GEMM-2: rx[comp][d2] += sum_n r[comp][n] * xt[n][d2] ----
#pragma unroll
        for (int ks = 0; ks < 2; ++ks) {
            short8v af = *(const short8v*)(rl + lm * 128 + ((ks * 32 + lh * 16) ^ ((lm & 7) << 4)));
#pragma unroll
            for (int nt = 0; nt < 4; ++nt) {
                short8v bv;
#pragma unroll
                for (int j = 0; j < 8; ++j) {
                    int pt = ks * 16 + lh * 8 + j;
                    bv[j] = *(const short*)(xt + pt * 256 + (((nt * 32 + lm) * 2) ^ ((pt & 7) << 4)));
                }
                rxacc[nt] = __builtin_amdgcn_mfma_f32_32x32x16_bf16(af, bv, rxacc[nt], 0, 0, 0);
            }
        }
    }

    // ---- dem: reduce over the 32 cols (pts) of each half ----
#pragma unroll
    for (int r = 0; r < 16; ++r) {
        float v = demacc[r];
        v += __shfl_xor(v, 1, 64);  v += __shfl_xor(v, 2, 64);
        v += __shfl_xor(v, 4, 64);  v += __shfl_xor(v, 8, 64);
        v += __shfl_xor(v, 16, 64);
        demacc[r] = v;
    }
    float* demsc = (float*)(smem + DEM_BASE);
    if (lm == 0) {
#pragma unroll
        for (int r = 0; r < 16; ++r)
            demsc[w * KC + (r & 3) + 8 * (r >> 2) + 4 * lh] = demacc[r];
    }

    // ---- block reduce rx partials: waves 1..3 -> 16KB regions, wave 0 sums ----
    __syncthreads();
    if (w > 0) {
        unsigned char* dst = smem + (w - 1) * 16384 + l * 256;
#pragma unroll
        for (int nt = 0; nt < 4; ++nt)
#pragma unroll
            for (int q = 0; q < 4; ++q) {
                float4 t4 = { rxacc[nt][q * 4 + 0], rxacc[nt][q * 4 + 1],
                              rxacc[nt][q * 4 + 2], rxacc[nt][q * 4 + 3] };
                *(float4*)(dst + ((nt * 64 + q * 16) ^ ((l & 7) << 4))) = t4;
            }
    }
    __syncthreads();
    if (w == 0) {
#pragma unroll
        for (int ww = 0; ww < 3; ++ww) {
            unsigned char* src = smem + ww * 16384 + l * 256;
#pragma unroll
            for (int nt = 0; nt < 4; ++nt)
#pragma unroll
                for (int q = 0; q < 4; ++q) {
                    float4 t4 = *(const float4*)(src + ((nt * 64 + q * 16) ^ ((l & 7) << 4)));
                    rxacc[nt][q * 4 + 0] += t4.x;  rxacc[nt][q * 4 + 1] += t4.y;
                    rxacc[nt][q * 4 + 2] += t4.z;  rxacc[nt][q * 4 + 3] += t4.w;
                }
        }
#pragma unroll
        for (int nt = 0; nt < 4; ++nt)
#pragma unroll
            for (int r = 0; r < 16; ++r) {
                int comp = (r & 3) + 8 * (r >> 2) + 4 * lh;
                int d2 = nt * 32 + lm;
                atomicAdd(&acc[KC + comp * 128 + d2], rxacc[nt][r]);
            }
        if (l < KC)
            atomicAdd(&acc[l], demsc[l] + demsc[KC + l] + demsc[2 * KC + l] + demsc[3 * KC + l]);
    }
}

__global__ void gmm_finalize(const float* __restrict__ acc, float* __restrict__ out) {
    int t = threadIdx.x + blockIdx.x * blockDim.x;
    if (t >= KC * DIM) return;
    int k = t >> 6, d = t & 63;
    float dm  = acc[k];
    float iv  = 1.0f / dm;
    float rx  = acc[KC + k * 128 + d];
    float rx2 = acc[KC + k * 128 + 64 + d];
    float muv = rx * iv;
    float vav = rx2 * iv - muv * muv;
    out[k * 129 + 1 + d]  = muv;
    out[k * 129 + 65 + d] = vav;
    if (d == 0) out[k * 129] = dm * (1.0f / (float)NPTS);
}

extern "C" void kernel_launch(void* const* d_in, const int* in_sizes, int n_in,
                              void* d_out, int out_size, void* d_ws, size_t ws_size,
                              hipStream_t stream) {
    const float* X   = (const float*)d_in[0];
    const float* mu  = (const float*)d_in[1];
    const float* var = (const float*)d_in[2];
    const float* pi  = (const float*)d_in[3];

    short* W   = (short*)d_ws;
    float* C   = (float*)((char*)d_ws + 8192);
    float* acc = (float*)((char*)d_ws + 8320);
    float* out = (float*)d_out;

    (void)hipMemsetAsync(acc, 0, ACC_FLOATS * sizeof(float), stream);
    gmm_prep<<<16, 256, 0, stream>>>(mu, var, pi, W, C);
    gmm_main<<<GRIDX, 256, 0, stream>>>(X, W, C, acc);
    gmm_finalize<<<8, 256, 0, stream>>>(acc, out);
}